// Round 8
// baseline (76.117 us; speedup 1.0000x reference)
//
#include <hip/hip_runtime.h>
#include <hip/hip_bf16.h>

// Problem constants (KANLayer): B=8192, I=256, O=256, NUM_BASIS=7, ORDER=3
#define B_SZ 8192
#define I_SZ 256
#define O_SZ 256
#define KDIM 2048  // I_SZ * 8  (7 basis + 1 silu per input feature)
#define BM 32      // rows per block
#define BN 128     // output cols per block
#define KTO 128    // outer K-tile (16 features)
#define NTO 16     // KDIM / KTO
#define NPART 128  // min/max partial rows

typedef __bf16 bf16x8 __attribute__((ext_vector_type(8)));
typedef float f32x4 __attribute__((ext_vector_type(4)));

// Kernel 1: per-column min/max partials. 128 blocks x 256 threads; block
// handles 64 rows via float4 loads (ILP), LDS-reduce over 4 row-subgroups,
// plain stores of one partial row per block (no atomics, no memset needed).
__global__ __launch_bounds__(256) void minmax_partial(
    const float* __restrict__ x, float* __restrict__ pmin,
    float* __restrict__ pmax) {
  const int cg = threadIdx.x & 63;  // column group (4 cols via float4)
  const int rs = threadIdx.x >> 6;  // row subgroup 0..3
  const int r0 = blockIdx.x * 64;
  const float* p = x + (size_t)(r0 + rs) * I_SZ + cg * 4;
  float4 mn = {1e30f, 1e30f, 1e30f, 1e30f};
  float4 mx = {-1e30f, -1e30f, -1e30f, -1e30f};
#pragma unroll
  for (int k = 0; k < 16; ++k) {
    const float4 v = *reinterpret_cast<const float4*>(p + (size_t)k * 4 * I_SZ);
    mn.x = fminf(mn.x, v.x); mn.y = fminf(mn.y, v.y);
    mn.z = fminf(mn.z, v.z); mn.w = fminf(mn.w, v.w);
    mx.x = fmaxf(mx.x, v.x); mx.y = fmaxf(mx.y, v.y);
    mx.z = fmaxf(mx.z, v.z); mx.w = fmaxf(mx.w, v.w);
  }
  __shared__ float rmn[4][I_SZ], rmx[4][I_SZ];
  *reinterpret_cast<float4*>(&rmn[rs][cg * 4]) = mn;
  *reinterpret_cast<float4*>(&rmx[rs][cg * 4]) = mx;
  __syncthreads();
  if (threadIdx.x < 64) {
    float4 a, b;
    const int c0 = threadIdx.x * 4;
    a.x = fminf(fminf(rmn[0][c0+0], rmn[1][c0+0]), fminf(rmn[2][c0+0], rmn[3][c0+0]));
    a.y = fminf(fminf(rmn[0][c0+1], rmn[1][c0+1]), fminf(rmn[2][c0+1], rmn[3][c0+1]));
    a.z = fminf(fminf(rmn[0][c0+2], rmn[1][c0+2]), fminf(rmn[2][c0+2], rmn[3][c0+2]));
    a.w = fminf(fminf(rmn[0][c0+3], rmn[1][c0+3]), fminf(rmn[2][c0+3], rmn[3][c0+3]));
    b.x = fmaxf(fmaxf(rmx[0][c0+0], rmx[1][c0+0]), fmaxf(rmx[2][c0+0], rmx[3][c0+0]));
    b.y = fmaxf(fmaxf(rmx[0][c0+1], rmx[1][c0+1]), fmaxf(rmx[2][c0+1], rmx[3][c0+1]));
    b.z = fmaxf(fmaxf(rmx[0][c0+2], rmx[1][c0+2]), fmaxf(rmx[2][c0+2], rmx[3][c0+2]));
    b.w = fmaxf(fmaxf(rmx[0][c0+3], rmx[1][c0+3]), fmaxf(rmx[2][c0+3], rmx[3][c0+3]));
    *reinterpret_cast<float4*>(&pmin[blockIdx.x * I_SZ + c0]) = a;
    *reinterpret_cast<float4*>(&pmax[blockIdx.x * I_SZ + c0]) = b;
  }
}

// Kernel 2: pack weights -> Wp[o, i*8+m] bf16, pre-swizzled (unit ^= o&7),
// PLUS (block 0) reduce the min/max partials into per-column scale pair
// (rhw, -centre*rhw) so the GEMM computes xn via one fma.
__global__ void pack_W(const float* __restrict__ bw,
                       const float* __restrict__ sw,
                       const float* __restrict__ coeff,
                       __hip_bfloat16* __restrict__ W,
                       const float* __restrict__ pmin,
                       const float* __restrict__ pmax,
                       float* __restrict__ cenrhw) {
  const int idx = blockIdx.x * blockDim.x + threadIdx.x;  // 0..O*I-1
  const int i = idx & (I_SZ - 1);
  const int o = idx >> 8;
  const float s = sw[idx];
  union { __hip_bfloat16 h[8]; float4 f4; } u;
#pragma unroll
  for (int m = 0; m < 7; ++m)
    u.h[m] = __float2bfloat16(coeff[(size_t)idx * 7 + m] * s);
  u.h[7] = __float2bfloat16(bw[idx]);
  const size_t off = (size_t)o * KDIM + (size_t)((i ^ (o & 7)) << 3);
  *reinterpret_cast<float4*>(&W[off]) = u.f4;

  if (blockIdx.x == 0) {
    const int c = threadIdx.x;
    float mn = 1e30f, mx = -1e30f;
#pragma unroll 8
    for (int p = 0; p < NPART; ++p) {
      mn = fminf(mn, pmin[p * I_SZ + c]);
      mx = fmaxf(mx, pmax[p * I_SZ + c]);
    }
    const float width = fmaxf(mx - mn, 0.01f);
    const float rhw = 2.0f / width;
    cenrhw[2 * c]     = rhw;
    cenrhw[2 * c + 1] = -0.5f * (mx + mn) * rhw;
  }
}

// ---- async global->LDS 16B copy ----
__device__ __forceinline__ void async16(const __hip_bfloat16* g, __hip_bfloat16* l) {
  __builtin_amdgcn_global_load_lds(
      (const __attribute__((address_space(1))) void*)g,
      (__attribute__((address_space(3))) void*)l, 16, 0, 0);
}

// Kernel 3: fused basis-build + GEMM, A-fragments built IN REGISTERS.
// For mfma_16x16x32_bf16, lane l holds A[row=l&15][k=(l>>4)*8..+7] — exactly
// one feature's 8 packed values (7 basis + silu). Each lane evaluates the
// basis for its own (row, feature) pair directly into the fragment: no A-LDS
// round-trip, no barrier gating A. B (weights) staged to LDS in KT=128 tiles
// (one barrier per 4 MFMA sub-steps); x register-prefetched one tile ahead.
__global__ __launch_bounds__(256, 2) void gemm_fused(
    const float* __restrict__ x, const __hip_bfloat16* __restrict__ W,
    const float* __restrict__ cenrhw, const float* __restrict__ bias,
    float* __restrict__ out) {
  __shared__ __align__(16) __hip_bfloat16 Blds[2][BN * KTO];   // 2 x 32KB
  __shared__ float2 scl[I_SZ];                                  // 2KB

  const int t = threadIdx.x;
  const int lane = t & 63;
  const int wave = t >> 6;            // 0..3 -> n-offset 32*wave
  const int fr = lane & 15, fk = lane >> 4;

  // XCD-aware bijective swizzle (512 blocks, %8==0)
  const int bid = blockIdx.x;
  const int swz = (bid & 7) * 64 + (bid >> 3);
  const int bm = swz >> 1, bn = swz & 1;
  const int r0 = bm * BM;    // batch-row base
  const int c0 = bn * BN;    // output-col base

  scl[t] = reinterpret_cast<const float2*>(cenrhw)[t];

  // B staging: thread t covers 16B-units u = t + 256q (q=0..7);
  // row = u>>4 (0..127), useg = u&15. LDS linear; source pre-swizzled.
  const __hip_bfloat16* gbase =
      W + (size_t)(c0 + (t >> 4)) * KDIM + (t & 15) * 8;

  auto stageB = [&](int buf, int kt) {
    const __hip_bfloat16* g = gbase + kt * KTO;
    __hip_bfloat16* l = &Blds[buf][t * 8];
#pragma unroll
    for (int q = 0; q < 8; ++q)
      async16(g + (size_t)16 * q * KDIM, l + 2048 * q);
  };

  // x access: lane needs x[r0+fr+16m][kt*16 + ss*4 + fk]
  const float* xq = x + (size_t)(r0 + fr) * I_SZ + fk;

  f32x4 acc[2][2] = {{{0.f,0.f,0.f,0.f},{0.f,0.f,0.f,0.f}},
                     {{0.f,0.f,0.f,0.f},{0.f,0.f,0.f,0.f}}};

  // closed-form uniform cubic B-spline (== reference's truncated de Boor):
  // cell c = floor((xn+1)*5) capped at 6, u = frac; slots c-3..c get q0..q3
  // (x 1/6); zero for sp>7. Produces the 8-bf16 A-fragment directly.
  auto evalOne = [&](float xv, float2 s2) -> bf16x8 {
    const float xn = __builtin_fmaf(xv, s2.x, s2.y);   // in [-1,1]
    const float sp = __builtin_fmaf(xn, 5.0f, 5.0f);   // in [0,10]
    const float c6 = fminf(floorf(sp), 6.0f);
    const int ci = (int)c6;
    const float u = sp - c6;
    const float zm = (sp > 7.0f) ? 0.0f : (1.0f / 6.0f);
    const float u2 = u * u;
    const float u3 = u2 * u;
    const float t1 = 1.0f - u;
    const float q3 = u3 * zm;
    const float q0 = (t1 * t1) * (t1 * zm);
    float h2 = __builtin_fmaf(-3.0f, u, 3.0f);
    h2 = __builtin_fmaf(h2, u, 3.0f);
    h2 = __builtin_fmaf(h2, u, 1.0f);                   // -3u^3+3u^2+3u+1
    const float q2 = h2 * zm;
    float h1 = __builtin_fmaf(3.0f, u, -6.0f);
    h1 = __builtin_fmaf(h1, u2, 4.0f);                  // 3u^3-6u^2+4
    const float q1 = h1 * zm;
    const float silu = xn * __builtin_amdgcn_rcpf(1.0f + __expf(-xn));
    union { __hip_bfloat16 h[8]; bf16x8 v; } uu;
#pragma unroll
    for (int j = 0; j < 7; ++j) {
      float v = 0.0f;
      v = (ci == j + 3) ? q0 : v;
      v = (ci == j + 2) ? q1 : v;
      v = (ci == j + 1) ? q2 : v;
      v = (ci == j)     ? q3 : v;
      uu.h[j] = __float2bfloat16(v);
    }
    uu.h[7] = __float2bfloat16(silu);
    return uu.v;
  };

  auto computeTile = [&](int buf, int kt, const float (&xv)[8]) {
    const __hip_bfloat16* L = Blds[buf];
    const int brow = wave * 32 + fr;        // B rows (out cols) for n=0
    const int bswz = brow & 7;              // same for brow+16
#pragma unroll
    for (int ss = 0; ss < 4; ++ss) {
      const float2 s2 = scl[kt * 16 + ss * 4 + fk];
      const bf16x8 a0 = evalOne(xv[ss], s2);
      const bf16x8 a1 = evalOne(xv[4 + ss], s2);
      const int u = ((ss << 2) | fk) ^ bswz;
      const bf16x8 b0 =
          *reinterpret_cast<const bf16x8*>(&L[brow * KTO + u * 8]);
      const bf16x8 b1 =
          *reinterpret_cast<const bf16x8*>(&L[(brow + 16) * KTO + u * 8]);
      acc[0][0] = __builtin_amdgcn_mfma_f32_16x16x32_bf16(a0, b0, acc[0][0], 0, 0, 0);
      acc[0][1] = __builtin_amdgcn_mfma_f32_16x16x32_bf16(a0, b1, acc[0][1], 0, 0, 0);
      acc[1][0] = __builtin_amdgcn_mfma_f32_16x16x32_bf16(a1, b0, acc[1][0], 0, 0, 0);
      acc[1][1] = __builtin_amdgcn_mfma_f32_16x16x32_bf16(a1, b1, acc[1][1], 0, 0, 0);
    }
  };

  // prologue: x for tile 0 + stage B tile 0
  float xva[8], xvb[8];
#pragma unroll
  for (int j = 0; j < 4; ++j) {
    xva[j]     = xq[j * 4];
    xva[4 + j] = xq[16 * I_SZ + j * 4];
  }
  stageB(0, 0);
  __syncthreads();   // scl visible + stage(0) drained (implicit vmcnt 0)

  for (int kt = 0; kt < NTO; ++kt) {
    const int buf = kt & 1;
    if (kt + 1 < NTO) {
      stageB(buf ^ 1, kt + 1);          // in flight across this tile's compute
      const int o = (kt + 1) * 16;
#pragma unroll
      for (int j = 0; j < 4; ++j) {
        xvb[j]     = xq[o + j * 4];
        xvb[4 + j] = xq[16 * I_SZ + o + j * 4];
      }
    }
    computeTile(buf, kt, xva);
    if (kt + 1 < NTO) {
      __syncthreads();                  // stage(kt+1) done + buf free for kt+2
#pragma unroll
      for (int j = 0; j < 8; ++j) xva[j] = xvb[j];
    }
  }

  // epilogue: C/D layout col=lane&15, row=(lane>>4)*4+reg  [m89/m91]
#pragma unroll
  for (int m = 0; m < 2; ++m)
#pragma unroll
    for (int n = 0; n < 2; ++n) {
      const int col = c0 + wave * 32 + n * 16 + fr;
      const float bc = bias[col];
#pragma unroll
      for (int r = 0; r < 4; ++r) {
        const int row = r0 + m * 16 + fk * 4 + r;
        out[(size_t)row * O_SZ + col] = acc[m][n][r] + bc;
      }
    }
}

extern "C" void kernel_launch(void* const* d_in, const int* in_sizes, int n_in,
                              void* d_out, int out_size, void* d_ws, size_t ws_size,
                              hipStream_t stream) {
  const float* x     = (const float*)d_in[0];
  const float* bw    = (const float*)d_in[1];
  const float* sw    = (const float*)d_in[2];
  const float* coeff = (const float*)d_in[3];
  const float* bias  = (const float*)d_in[4];
  float* out = (float*)d_out;

  char* ws = (char*)d_ws;
  __hip_bfloat16* Wbuf = (__hip_bfloat16*)ws;                    // 1 MiB
  float* pmin   = (float*)(ws + (size_t)O_SZ * KDIM * 2);        // 128 KiB
  float* pmax   = pmin + NPART * I_SZ;                           // 128 KiB
  float* cenrhw = pmax + NPART * I_SZ;                           // 2 KiB

  minmax_partial<<<NPART, 256, 0, stream>>>(x, pmin, pmax);
  pack_W<<<(O_SZ * I_SZ) / 256, 256, 0, stream>>>(bw, sw, coeff, Wbuf,
                                                  pmin, pmax, cenrhw);
  gemm_fused<<<(B_SZ / BM) * (O_SZ / BN), 256, 0, stream>>>(x, Wbuf, cenrhw,
                                                            bias, out);
}

// Round 9
// 65.554 us; speedup vs baseline: 1.1611x; 1.1611x over previous
//
#include <hip/hip_runtime.h>
#include <hip/hip_bf16.h>

// Problem constants (KANLayer): B=8192, I=256, O=256, NUM_BASIS=7, ORDER=3
#define B_SZ 8192
#define I_SZ 256
#define O_SZ 256
#define KDIM 2048  // I_SZ * 8  (7 basis + 1 silu per input feature)
#define BMB 128    // rows per block (4 waves x 32)
#define BNB 32     // output cols per block
#define KTO 128    // K per tile = 16 features
#define NTO 16     // KDIM / KTO
#define NPART 128  // min/max partial rows

typedef __bf16 bf16x8 __attribute__((ext_vector_type(8)));
typedef float f32x4 __attribute__((ext_vector_type(4)));

// Kernel 1: per-column min/max partials. 128 blocks x 256 threads; block
// handles 64 rows via float4 loads (ILP), LDS-reduce over 4 row-subgroups,
// plain stores of one partial row per block (no atomics, no memset needed).
__global__ __launch_bounds__(256) void minmax_partial(
    const float* __restrict__ x, float* __restrict__ pmin,
    float* __restrict__ pmax) {
  const int cg = threadIdx.x & 63;  // column group (4 cols via float4)
  const int rs = threadIdx.x >> 6;  // row subgroup 0..3
  const int r0 = blockIdx.x * 64;
  const float* p = x + (size_t)(r0 + rs) * I_SZ + cg * 4;
  float4 mn = {1e30f, 1e30f, 1e30f, 1e30f};
  float4 mx = {-1e30f, -1e30f, -1e30f, -1e30f};
#pragma unroll
  for (int k = 0; k < 16; ++k) {
    const float4 v = *reinterpret_cast<const float4*>(p + (size_t)k * 4 * I_SZ);
    mn.x = fminf(mn.x, v.x); mn.y = fminf(mn.y, v.y);
    mn.z = fminf(mn.z, v.z); mn.w = fminf(mn.w, v.w);
    mx.x = fmaxf(mx.x, v.x); mx.y = fmaxf(mx.y, v.y);
    mx.z = fmaxf(mx.z, v.z); mx.w = fmaxf(mx.w, v.w);
  }
  __shared__ float rmn[4][I_SZ], rmx[4][I_SZ];
  *reinterpret_cast<float4*>(&rmn[rs][cg * 4]) = mn;
  *reinterpret_cast<float4*>(&rmx[rs][cg * 4]) = mx;
  __syncthreads();
  if (threadIdx.x < 64) {
    float4 a, b;
    const int c0 = threadIdx.x * 4;
    a.x = fminf(fminf(rmn[0][c0+0], rmn[1][c0+0]), fminf(rmn[2][c0+0], rmn[3][c0+0]));
    a.y = fminf(fminf(rmn[0][c0+1], rmn[1][c0+1]), fminf(rmn[2][c0+1], rmn[3][c0+1]));
    a.z = fminf(fminf(rmn[0][c0+2], rmn[1][c0+2]), fminf(rmn[2][c0+2], rmn[3][c0+2]));
    a.w = fminf(fminf(rmn[0][c0+3], rmn[1][c0+3]), fminf(rmn[2][c0+3], rmn[3][c0+3]));
    b.x = fmaxf(fmaxf(rmx[0][c0+0], rmx[1][c0+0]), fmaxf(rmx[2][c0+0], rmx[3][c0+0]));
    b.y = fmaxf(fmaxf(rmx[0][c0+1], rmx[1][c0+1]), fmaxf(rmx[2][c0+1], rmx[3][c0+1]));
    b.z = fmaxf(fmaxf(rmx[0][c0+2], rmx[1][c0+2]), fmaxf(rmx[2][c0+2], rmx[3][c0+2]));
    b.w = fmaxf(fmaxf(rmx[0][c0+3], rmx[1][c0+3]), fmaxf(rmx[2][c0+3], rmx[3][c0+3]));
    *reinterpret_cast<float4*>(&pmin[blockIdx.x * I_SZ + c0]) = a;
    *reinterpret_cast<float4*>(&pmax[blockIdx.x * I_SZ + c0]) = b;
  }
}

// Kernel 2: pack weights -> Wp[o, i*8+m] bf16, pre-swizzled (unit ^= o&7),
// PLUS (block 0) reduce the min/max partials into per-column scale pair
// (rhw, -centre*rhw) so the GEMM computes xn via one fma.
__global__ void pack_W(const float* __restrict__ bw,
                       const float* __restrict__ sw,
                       const float* __restrict__ coeff,
                       __hip_bfloat16* __restrict__ W,
                       const float* __restrict__ pmin,
                       const float* __restrict__ pmax,
                       float* __restrict__ cenrhw) {
  const int idx = blockIdx.x * blockDim.x + threadIdx.x;  // 0..O*I-1
  const int i = idx & (I_SZ - 1);
  const int o = idx >> 8;
  const float s = sw[idx];
  union { __hip_bfloat16 h[8]; float4 f4; } u;
#pragma unroll
  for (int m = 0; m < 7; ++m)
    u.h[m] = __float2bfloat16(coeff[(size_t)idx * 7 + m] * s);
  u.h[7] = __float2bfloat16(bw[idx]);
  const size_t off = (size_t)o * KDIM + (size_t)((i ^ (o & 7)) << 3);
  *reinterpret_cast<float4*>(&W[off]) = u.f4;

  if (blockIdx.x == 0) {
    const int c = threadIdx.x;
    float mn = 1e30f, mx = -1e30f;
#pragma unroll 8
    for (int p = 0; p < NPART; ++p) {
      mn = fminf(mn, pmin[p * I_SZ + c]);
      mx = fmaxf(mx, pmax[p * I_SZ + c]);
    }
    const float width = fmaxf(mx - mn, 0.01f);
    const float rhw = 2.0f / width;
    cenrhw[2 * c]     = rhw;
    cenrhw[2 * c + 1] = -0.5f * (mx + mn) * rhw;
  }
}

// ---- async global->LDS 16B copy ----
__device__ __forceinline__ void async16(const __hip_bfloat16* g, __hip_bfloat16* l) {
  __builtin_amdgcn_global_load_lds(
      (const __attribute__((address_space(1))) void*)g,
      (__attribute__((address_space(3))) void*)l, 16, 0, 0);
}

// Kernel 3: fused basis-build + GEMM, A-fragments built IN REGISTERS,
// waves M-SPLIT (each wave owns its own 32 rows -> zero eval redundancy).
// Block = 128 rows x 32 cols, 256 threads; grid 512 = 2 blocks/CU.
// B staged per K-tile as two [32 rows][64 elem] sub-tiles (128B row stride,
// 3-bit XOR swizzle = the measured-zero-conflict pattern). One barrier/tile.
__global__ __launch_bounds__(256, 2) void gemm_fused(
    const float* __restrict__ x, const __hip_bfloat16* __restrict__ W,
    const float* __restrict__ cenrhw, const float* __restrict__ bias,
    float* __restrict__ out) {
  __shared__ __align__(16) __hip_bfloat16 Blds[2][2][32 * 64];  // 16KB
  __shared__ float2 scl[I_SZ];                                   // 2KB

  const int t = threadIdx.x;
  const int lane = t & 63;
  const int wave = t >> 6;            // 0..3 -> row-offset 32*wave
  const int fr = lane & 15, fk = lane >> 4;

  // XCD-aware swizzle: 8 bn-panels of one bm-group adjacent on one XCD
  // -> x rows and W fully L2-resident per XCD.
  const int bid = blockIdx.x;
  const int swz = (bid & 7) * 64 + (bid >> 3);
  const int bm = swz >> 3, bn = swz & 7;   // bm 0..63, bn 0..7
  const int r0 = bm * BMB;   // batch-row base
  const int c0 = bn * BNB;   // output-col base

  scl[t] = reinterpret_cast<const float2*>(cenrhw)[t];

  // B staging: thread t covers (row=t>>3, useg=t&7) in both sub-tiles.
  const __hip_bfloat16* gb =
      W + (size_t)(c0 + (t >> 3)) * KDIM + (t & 7) * 8;

  auto stageB = [&](int buf, int kt) {
    const __hip_bfloat16* g = gb + kt * KTO;
    async16(g,      &Blds[buf][0][t * 8]);
    async16(g + 64, &Blds[buf][1][t * 8]);
  };

  // x access: lane evaluates rows (r0 + wave*32 + fr) and (+16), feature
  // kt*16 + ss*4 + fk.
  const float* xq = x + (size_t)(r0 + wave * 32 + fr) * I_SZ + fk;

  f32x4 acc[2][2] = {{{0.f,0.f,0.f,0.f},{0.f,0.f,0.f,0.f}},
                     {{0.f,0.f,0.f,0.f},{0.f,0.f,0.f,0.f}}};

  // closed-form uniform cubic B-spline (== reference's truncated de Boor):
  // cell c = floor((xn+1)*5) capped at 6, u = frac; slots c-3..c get q0..q3
  // (x 1/6); zero for sp>7. Produces the 8-bf16 A-fragment directly.
  auto evalOne = [&](float xv, float2 s2) -> bf16x8 {
    const float xn = __builtin_fmaf(xv, s2.x, s2.y);   // in [-1,1]
    const float sp = __builtin_fmaf(xn, 5.0f, 5.0f);   // in [0,10]
    const float c6 = fminf(floorf(sp), 6.0f);
    const int ci = (int)c6;
    const float u = sp - c6;
    const float zm = (sp > 7.0f) ? 0.0f : (1.0f / 6.0f);
    const float u2 = u * u;
    const float u3 = u2 * u;
    const float t1 = 1.0f - u;
    const float q3 = u3 * zm;
    const float q0 = (t1 * t1) * (t1 * zm);
    float h2 = __builtin_fmaf(-3.0f, u, 3.0f);
    h2 = __builtin_fmaf(h2, u, 3.0f);
    h2 = __builtin_fmaf(h2, u, 1.0f);                   // -3u^3+3u^2+3u+1
    const float q2 = h2 * zm;
    float h1 = __builtin_fmaf(3.0f, u, -6.0f);
    h1 = __builtin_fmaf(h1, u2, 4.0f);                  // 3u^3-6u^2+4
    const float q1 = h1 * zm;
    const float silu = xn * __builtin_amdgcn_rcpf(1.0f + __expf(-xn));
    union { __hip_bfloat16 h[8]; bf16x8 v; } uu;
#pragma unroll
    for (int j = 0; j < 7; ++j) {
      float v = 0.0f;
      v = (ci == j + 3) ? q0 : v;
      v = (ci == j + 2) ? q1 : v;
      v = (ci == j + 1) ? q2 : v;
      v = (ci == j)     ? q3 : v;
      uu.h[j] = __float2bfloat16(v);
    }
    uu.h[7] = __float2bfloat16(silu);
    return uu.v;
  };

  auto computeTile = [&](int buf, int kt, const float (&xv)[8]) {
#pragma unroll
    for (int ss = 0; ss < 4; ++ss) {
      const float2 s2 = scl[kt * 16 + ss * 4 + fk];
      const bf16x8 a0 = evalOne(xv[ss], s2);        // row wave*32+fr
      const bf16x8 a1 = evalOne(xv[4 + ss], s2);    // row wave*32+fr+16
      const __hip_bfloat16* L = Blds[buf][ss >> 1];
      const int klo = ((ss & 1) << 2) | fk;
      bf16x8 b[2];
#pragma unroll
      for (int n = 0; n < 2; ++n) {
        const int brow = n * 16 + fr;
        const int unit = klo ^ (brow & 7);
        b[n] = *reinterpret_cast<const bf16x8*>(&L[brow * 64 + unit * 8]);
      }
      acc[0][0] = __builtin_amdgcn_mfma_f32_16x16x32_bf16(a0, b[0], acc[0][0], 0, 0, 0);
      acc[0][1] = __builtin_amdgcn_mfma_f32_16x16x32_bf16(a0, b[1], acc[0][1], 0, 0, 0);
      acc[1][0] = __builtin_amdgcn_mfma_f32_16x16x32_bf16(a1, b[0], acc[1][0], 0, 0, 0);
      acc[1][1] = __builtin_amdgcn_mfma_f32_16x16x32_bf16(a1, b[1], acc[1][1], 0, 0, 0);
    }
  };

  // prologue: x for tile 0 + stage B tile 0
  float xva[8], xvb[8];
#pragma unroll
  for (int j = 0; j < 4; ++j) {
    xva[j]     = xq[j * 4];
    xva[4 + j] = xq[16 * I_SZ + j * 4];
  }
  stageB(0, 0);
  __syncthreads();   // scl visible + stage(0) drained

  for (int kt = 0; kt < NTO; ++kt) {
    const int buf = kt & 1;
    if (kt + 1 < NTO) {
      stageB(buf ^ 1, kt + 1);          // in flight across this tile's compute
      const int o = (kt + 1) * 16;
#pragma unroll
      for (int j = 0; j < 4; ++j) {
        xvb[j]     = xq[o + j * 4];
        xvb[4 + j] = xq[16 * I_SZ + o + j * 4];
      }
    }
    computeTile(buf, kt, xva);
    if (kt + 1 < NTO) {
      __syncthreads();                  // stage(kt+1) done + buf free
#pragma unroll
      for (int j = 0; j < 8; ++j) xva[j] = xvb[j];
    }
  }

  // epilogue: C/D layout col=lane&15, row=(lane>>4)*4+reg  [m89/m91]
#pragma unroll
  for (int m = 0; m < 2; ++m)
#pragma unroll
    for (int n = 0; n < 2; ++n) {
      const int col = c0 + n * 16 + fr;
      const float bc = bias[col];
#pragma unroll
      for (int r = 0; r < 4; ++r) {
        const int row = r0 + wave * 32 + m * 16 + fk * 4 + r;
        out[(size_t)row * O_SZ + col] = acc[m][n][r] + bc;
      }
    }
}

extern "C" void kernel_launch(void* const* d_in, const int* in_sizes, int n_in,
                              void* d_out, int out_size, void* d_ws, size_t ws_size,
                              hipStream_t stream) {
  const float* x     = (const float*)d_in[0];
  const float* bw    = (const float*)d_in[1];
  const float* sw    = (const float*)d_in[2];
  const float* coeff = (const float*)d_in[3];
  const float* bias  = (const float*)d_in[4];
  float* out = (float*)d_out;

  char* ws = (char*)d_ws;
  __hip_bfloat16* Wbuf = (__hip_bfloat16*)ws;                    // 1 MiB
  float* pmin   = (float*)(ws + (size_t)O_SZ * KDIM * 2);        // 128 KiB
  float* pmax   = pmin + NPART * I_SZ;                           // 128 KiB
  float* cenrhw = pmax + NPART * I_SZ;                           // 2 KiB

  minmax_partial<<<NPART, 256, 0, stream>>>(x, pmin, pmax);
  pack_W<<<(O_SZ * I_SZ) / 256, 256, 0, stream>>>(bw, sw, coeff, Wbuf,
                                                  pmin, pmax, cenrhw);
  gemm_fused<<<(B_SZ / BMB) * (O_SZ / BNB), 256, 0, stream>>>(x, Wbuf, cenrhw,
                                                              bias, out);
}